// Round 1
// baseline (275.059 us; speedup 1.0000x reference)
//
#include <hip/hip_runtime.h>
#include <math.h>

#define B_ 4
#define S_ 2048
#define D_ 1024
#define H_ 16
#define HD_ 64
#define ES_F 0.180336880111f    // 0.125 * log2(e), folded into Q
#define KF (-0.41524101186f)    // -log2(10000)/32

typedef unsigned short ushort_t;
typedef __attribute__((ext_vector_type(8))) short short8;    // 8 bf16 (MFMA A/B frag)
typedef __attribute__((ext_vector_type(4))) short short4_t;  // 4 bf16 packed store
typedef __attribute__((ext_vector_type(4))) float f32x4;     // 16x16 C/D frag
typedef __attribute__((ext_vector_type(16))) float f32x16;   // 32x32 C/D frag
typedef __attribute__((ext_vector_type(2))) unsigned uint2v;

typedef const void __attribute__((address_space(1))) gvoid;
typedef void __attribute__((address_space(3))) lvoid;

__device__ __forceinline__ ushort_t f2bf(float f) {
    union { float f; unsigned u; } v; v.f = f;
    unsigned r = (v.u + 0x7FFFu + ((v.u >> 16) & 1u)) >> 16;
    return (ushort_t)r;
}
__device__ __forceinline__ float fexp2(float x) {
#if __has_builtin(__builtin_amdgcn_exp2f)
    return __builtin_amdgcn_exp2f(x);   // raw v_exp_f32
#else
    return exp2f(x);
#endif
}
// pack two f32 -> bf16x2 (truncation) in one v_perm_b32
__device__ __forceinline__ unsigned pk2t(float a, float b) {
    union { float f; unsigned u; } A, Bv; A.f = a; Bv.f = b;
#if __has_builtin(__builtin_amdgcn_perm)
    return __builtin_amdgcn_perm(Bv.u, A.u, 0x07060302u);
#else
    return (A.u >> 16) | (Bv.u & 0xFFFF0000u);
#endif
}
__device__ __forceinline__ short8 mk_frag(unsigned a, unsigned b, unsigned c, unsigned d) {
    union { unsigned u[4]; short8 s; } t;
    t.u[0] = a; t.u[1] = b; t.u[2] = c; t.u[3] = d; return t.s;
}

// ---------------------------------------------------------------------------
// x fp32 -> bf16, 8 elems/thread
// ---------------------------------------------------------------------------
__global__ __launch_bounds__(256)
void cvt_x(const float* __restrict__ x, ushort_t* __restrict__ xb)
{
    const size_t i = ((size_t)blockIdx.x * 256 + threadIdx.x) * 8;
    float4 a = *(const float4*)&x[i];
    float4 b = *(const float4*)&x[i + 4];
    short8 o;
    o[0] = (short)f2bf(a.x); o[1] = (short)f2bf(a.y);
    o[2] = (short)f2bf(a.z); o[3] = (short)f2bf(a.w);
    o[4] = (short)f2bf(b.x); o[5] = (short)f2bf(b.y);
    o[6] = (short)f2bf(b.z); o[7] = (short)f2bf(b.w);
    *(short8*)&xb[i] = o;
}

// ---------------------------------------------------------------------------
// W[k][n] fp32 -> Wt[n][k] bf16 (64x64 tiles through LDS), all 4 weights
// ---------------------------------------------------------------------------
__global__ __launch_bounds__(256)
void cvt_wt4(const float* __restrict__ W0, const float* __restrict__ W1,
             const float* __restrict__ W2, const float* __restrict__ W3,
             ushort_t* __restrict__ T0, ushort_t* __restrict__ T1,
             ushort_t* __restrict__ T2, ushort_t* __restrict__ T3)
{
    const int z = blockIdx.z;
    const float* W = (z == 0) ? W0 : (z == 1) ? W1 : (z == 2) ? W2 : W3;
    ushort_t* Wt = (z == 0) ? T0 : (z == 1) ? T1 : (z == 2) ? T2 : T3;

    __shared__ __align__(16) float T[64 * 68];
    const int t = threadIdx.x;
    const int k0 = blockIdx.y * 64, n0 = blockIdx.x * 64;
    const int row = t >> 2, c0 = (t & 3) * 16;
#pragma unroll
    for (int u = 0; u < 4; ++u)
        *(float4*)&T[row * 68 + c0 + u * 4] =
            *(const float4*)&W[(size_t)(k0 + row) * D_ + n0 + c0 + u * 4];
    __syncthreads();
    const int n = t >> 2, kc = (t & 3) * 16;
    short8 o0, o1;
#pragma unroll
    for (int kk = 0; kk < 8; ++kk) o0[kk] = (short)f2bf(T[(kc + kk) * 68 + n]);
#pragma unroll
    for (int kk = 0; kk < 8; ++kk) o1[kk] = (short)f2bf(T[(kc + 8 + kk) * 68 + n]);
    *(short8*)&Wt[(size_t)(n0 + n) * D_ + k0 + kc] = o0;
    *(short8*)&Wt[(size_t)(n0 + n) * D_ + k0 + kc + 8] = o1;
}

// ---------------------------------------------------------------------------
// bf16 MFMA GEMM (B^T input): C[m][n] = sum_k A[m][k] * Wt[n][k]
// 256x256 tile, BK=64, 512 thr (8 waves, 2M x 4N), 8-phase counted-vmcnt
// schedule (T3+T4+T5 per guide §5.5): per K-tile 4 quadrant-phases, each
// {ds_read frags || 1 half-tile global_load_lds -> barrier -> lgkmcnt(0) ->
// setprio(1) 8xMFMA setprio(0) -> barrier}; vmcnt(4) once per K-tile (never
// 0 until final drain).  LDS 128 KiB: 2 buffers x (A 256x64 + B 256x64) bf16
// with the verified source-side XOR swizzle (T2).  Fragments deduplicated:
// A held across its two qn-phases, B held across its two qm-phases -> 24
// unique ds_read_b128 per tile per wave.
//
// Staging units per K-tile (128 rows each, 2 gload_lds/wave):
//   AU0 = A rows {0-63,128-191}, AU1 = {64-127,192-255}
//   BU0 = B rows {0-31,64-95,128-159,192-223}, BU1 = the other 128
// During tile u (bufs p=u&1): ph0 stages (u+1).AU1->p^1, ph1 (u+1).BU1->p^1,
// ph2 (u+2).AU0->p, ph3 (u+2).BU0->p.  Region written in phase j was last
// read in phase j-1 (barrier-separated), so in-flight writes never race the
// reads; vmcnt(4) at ph3 guarantees everything except the newest 2 units
// has landed before the next tile's reads.
//
// C/D layout (32x32x16): col=lane&31, row=(reg&3)+8*(reg>>2)+4*(lane>>5) ->
// thread owns 4 CONSECUTIVE tokens per reg-group (RoPE angle recurrence).
// Grid: x = m-tile (32), y = n-tile (4), z = weight select.
// mode 0: RoPE * ES -> Qb ; 1: RoPE -> Kb ; 2: -> Vt [b][h][d][s] ; 3: fp32 out
// ---------------------------------------------------------------------------

#define FENCE asm volatile("" ::: "memory")
#define BARRIER { FENCE; __builtin_amdgcn_s_barrier(); FENCE; }
#define WAITLGKM { asm volatile("s_waitcnt lgkmcnt(0)" ::: "memory"); \
                   __builtin_amdgcn_sched_barrier(0); }
#define VMCNT4 asm volatile("s_waitcnt vmcnt(4)" ::: "memory")
#define VMCNT0 asm volatile("s_waitcnt vmcnt(0)" ::: "memory")

// swizzled ds_read_b128 of one MFMA fragment (row%8 XOR on 16B chunks)
#define DS_A(Ab, qm, tm, ks)                                                   \
    (*(const short8*)&(Ab)[(wr * 128 + (qm) * 64 + (tm) * 32 + lq) * 64 +      \
                           ((((ks) * 2 + hl) ^ (lq & 7)) << 3)])
#define DS_B(Bb, qn, ks)                                                       \
    (*(const short8*)&(Bb)[(wc * 64 + (qn) * 32 + lq) * 64 +                   \
                           ((((ks) * 2 + hl) ^ (lq & 7)) << 3)])

// stage one 128-row unit (2 gload_lds / wave); LDS dest linear, swizzle on src
#define STAGE_A2(h, kk, dst) {                                                 \
    const int gA0_ = (h) * 8 + w, gA1_ = (h) * 8 + 16 + w;                     \
    __builtin_amdgcn_global_load_lds((gvoid*)(aSrc + (size_t)gA0_ * (8 * D_) + (kk)), \
        (lvoid*)&(dst)[gA0_ * (8 * 64)], 16, 0, 0);                            \
    __builtin_amdgcn_global_load_lds((gvoid*)(aSrc + (size_t)gA1_ * (8 * D_) + (kk)), \
        (lvoid*)&(dst)[gA1_ * (8 * 64)], 16, 0, 0); }
#define STAGE_B2(h, kk, dst) {                                                 \
    const int gB0_ = (w & 3) + ((w >> 2) * 8) + (h) * 4, gB1_ = gB0_ + 16;     \
    __builtin_amdgcn_global_load_lds((gvoid*)(bSrc + (size_t)gB0_ * (8 * D_) + (kk)), \
        (lvoid*)&(dst)[gB0_ * (8 * 64)], 16, 0, 0);                            \
    __builtin_amdgcn_global_load_lds((gvoid*)(bSrc + (size_t)gB1_ * (8 * D_) + (kk)), \
        (lvoid*)&(dst)[gB1_ * (8 * 64)], 16, 0, 0); }

#define MFMA8(qm, qn) {                                                        \
    __builtin_amdgcn_s_setprio(1);                                             \
    _Pragma("unroll") for (int ks = 0; ks < 4; ++ks)                           \
    _Pragma("unroll") for (int tm = 0; tm < 2; ++tm)                           \
        acc[qm][qn][tm] = __builtin_amdgcn_mfma_f32_32x32x16_bf16(             \
            fa[tm][ks], fb[qn][ks], acc[qm][qn][tm], 0, 0, 0);                 \
    __builtin_amdgcn_s_setprio(0); }

// one K-tile: 4 phases.  ST0..ST3 are the per-phase staging statements,
// POST is the once-per-tile vmcnt (placed after the last MFMA cluster).
#define KTILE(Ab, Bb, ST0, ST1, ST2, ST3, POST)                                \
{                                                                              \
    short8 fa[2][4], fb[2][4];                                                 \
    /* ph0 (qm0,qn0): load A(qm0)+B(qn0) */                                    \
    _Pragma("unroll") for (int tm = 0; tm < 2; ++tm)                           \
    _Pragma("unroll") for (int ks = 0; ks < 4; ++ks)                           \
        fa[tm][ks] = DS_A(Ab, 0, tm, ks);                                      \
    _Pragma("unroll") for (int ks = 0; ks < 4; ++ks)                           \
        fb[0][ks] = DS_B(Bb, 0, ks);                                           \
    ST0;                                                                       \
    BARRIER; WAITLGKM; MFMA8(0, 0);                                            \
    BARRIER;                                                                   \
    /* ph1 (qm0,qn1): load B(qn1), reuse A */                                  \
    _Pragma("unroll") for (int ks = 0; ks < 4; ++ks)                           \
        fb[1][ks] = DS_B(Bb, 1, ks);                                           \
    ST1;                                                                       \
    BARRIER; WAITLGKM; MFMA8(0, 1);                                            \
    BARRIER;                                                                   \
    /* ph2 (qm1,qn0): load A(qm1), reuse B(qn0) */                             \
    _Pragma("unroll") for (int tm = 0; tm < 2; ++tm)                           \
    _Pragma("unroll") for (int ks = 0; ks < 4; ++ks)                           \
        fa[tm][ks] = DS_A(Ab, 1, tm, ks);                                      \
    ST2;                                                                       \
    BARRIER; WAITLGKM; MFMA8(1, 0);                                            \
    BARRIER;                                                                   \
    /* ph3 (qm1,qn1): no loads */                                              \
    ST3;                                                                       \
    BARRIER; WAITLGKM; MFMA8(1, 1);                                            \
    POST;                                                                      \
    BARRIER;                                                                   \
}

__global__ __launch_bounds__(512, 2)
void gemm_bt(const ushort_t* __restrict__ A,
             const ushort_t* __restrict__ W0, const ushort_t* __restrict__ W1,
             const ushort_t* __restrict__ W2,
             void* __restrict__ d0, void* __restrict__ d1, void* __restrict__ d2,
             const int mode_base)
{
    __shared__ __align__(16) ushort_t As[2 * 256 * 64];   // 64 KiB
    __shared__ __align__(16) ushort_t Bs[2 * 256 * 64];   // 64 KiB

    const int tid = threadIdx.x;
    const int lane = tid & 63;
    const int hl = lane >> 5;          // lane half
    const int lq = lane & 31;          // row/col within 32-tile
    const int w = tid >> 6;            // wave 0..7
    const int wr = w >> 2, wc = w & 3; // 2M x 4N wave grid
    const int z = blockIdx.z;
    const ushort_t* Wt = (z == 0) ? W0 : (z == 1) ? W1 : W2;
    const int mode = mode_base + z;
    const int m0 = blockIdx.x * 256, n0 = blockIdx.y * 256;

    const f32x16 zv16 = {0,0,0,0,0,0,0,0,0,0,0,0,0,0,0,0};
    f32x16 acc[2][2][2];
#pragma unroll
    for (int a = 0; a < 2; ++a)
#pragma unroll
        for (int b = 0; b < 2; ++b)
#pragma unroll
            for (int c = 0; c < 2; ++c) acc[a][b][c] = zv16;

    const int srow = lane >> 3;              // row within 8-row staging group
    const int spc  = lane & 7;               // phys chunk this lane fills
    const int sch  = (spc ^ srow) * 8;       // logical chunk to fetch (swizzle)

    const ushort_t* aSrc = A  + (size_t)(m0 + srow) * D_ + sch;
    const ushort_t* bSrc = Wt + (size_t)(n0 + srow) * D_ + sch;
    ushort_t* A0 = As;            ushort_t* A1 = As + 256 * 64;
    ushort_t* B0 = Bs;            ushort_t* B1 = Bs + 256 * 64;

    // prologue: tile0 all 4 units + tile1 AU0/BU0; drain tile0, keep 2 units
    // in flight (steady-state invariant).
    STAGE_A2(0, 0, A0);  STAGE_B2(0, 0, B0);
    STAGE_A2(1, 0, A0);  STAGE_B2(1, 0, B0);
    STAGE_A2(0, 64, A1); STAGE_B2(0, 64, B1);
    VMCNT4;
    BARRIER;

#pragma unroll 1
    for (int it = 0; it < 8; ++it) {
        const int u0 = 2 * it;
        const int kA = (u0 + 1) * 64;   // k-offset of tile u0+1
        const int kB = (u0 + 2) * 64;   // tile u0+2
        const int kC = (u0 + 3) * 64;   // tile u0+3
        const bool st = (it < 7);
        // tile u0 (even, bufs A0/B0)
        KTILE(A0, B0,
              STAGE_A2(1, kA, A1),
              STAGE_B2(1, kA, B1),
              if (st) STAGE_A2(0, kB, A0),
              if (st) STAGE_B2(0, kB, B0),
              if (st) { VMCNT4; } else { VMCNT0; });
        // tile u0+1 (odd, bufs A1/B1)
        KTILE(A1, B1,
              if (st) STAGE_A2(1, kB, A0),
              if (st) STAGE_B2(1, kB, B0),
              if (st) STAGE_A2(0, kC, A1),
              if (st) STAGE_B2(0, kC, B1),
              if (st) { VMCNT4; });
    }

    // epilogue: C[m][n], m = m0+wr*128+qm*64+tm*32 + 4hl+8g+r,
    //                    n = n0+wc*64+qn*32+lq
#pragma unroll
    for (int qn = 0; qn < 2; ++qn) {
        const int n = n0 + wc * 64 + qn * 32 + lq;
        const int h = n >> 6, dd = n & 63;
        // RoPE per-column constants (modes 0/1 only)
        const int j = dd >> 1;
        const float invf = exp2f(KF * (float)j);
        float sd, cd;
        __sincosf(invf, &sd, &cd);      // delta rotation (token step)
#pragma unroll
        for (int qm = 0; qm < 2; ++qm)
#pragma unroll
        for (int tm = 0; tm < 2; ++tm) {
            const int mb = m0 + wr * 128 + qm * 64 + tm * 32 + 4 * hl;
            if (mode == 3) {
#pragma unroll
                for (int g = 0; g < 4; ++g)
#pragma unroll
                    for (int r = 0; r < 4; ++r)
                        ((float*)d0)[(size_t)(mb + 8 * g + r) * D_ + n] =
                            acc[qm][qn][tm][4 * g + r];
            } else if (mode == 2) {
#pragma unroll
                for (int g = 0; g < 4; ++g) {
                    const int m_base = mb + 8 * g;
                    const int bb = m_base >> 11, s0 = m_base & (S_ - 1);
                    short4_t pk;
#pragma unroll
                    for (int r = 0; r < 4; ++r)
                        pk[r] = (short)f2bf(acc[qm][qn][tm][4 * g + r]);
                    *(short4_t*)&((ushort_t*)d2)[(((size_t)bb * H_ + h) * HD_ + dd) * S_ + s0] = pk;
                }
            } else {
                ushort_t* dst = (mode == 0) ? (ushort_t*)d0 : (ushort_t*)d1;
                const float sc = (mode == 0) ? ES_F : 1.0f;
#pragma unroll
                for (int g = 0; g < 4; ++g) {
                    const int m_base = mb + 8 * g;
                    const int bb = m_base >> 11, s0 = m_base & (S_ - 1);
                    float sn, cs;
                    __sincosf((float)s0 * invf, &sn, &cs);
                    ushort_t* dp = &dst[(((size_t)bb * H_ + h) * S_ + s0) * HD_ + dd];
#pragma unroll
                    for (int r = 0; r < 4; ++r) {
                        const float val = acc[qm][qn][tm][4 * g + r];
                        const float par = __shfl_xor(val, 1);
                        const float res = ((dd & 1) == 0) ? (val * cs - par * sn)
                                                          : (par * sn + val * cs);
                        dp[(size_t)r * HD_] = f2bf(res * sc);
                        const float c2 = cs * cd - sn * sd;   // advance token angle
                        sn = sn * cd + cs * sd;
                        cs = c2;
                    }
                }
            }
        }
    }
}

// ---------------------------------------------------------------------------
// MFMA flash attention, S^T formulation, P fully in registers.
// Grid: x = head-linear (64) -> id%8 = head%8 (XCD K/V L2 locality).
// y = causal pair (8). Block = 4 waves; two 128-row q-tiles per block
// (pair j, 15-j) -> uniform 34 stages/block. S^T = K Q^T (32x32x16); P^T
// built in-register; half-swap via v_permlane32_swap (VALU pipe, one op
// yields both frag words) with shfl fallback. O^T = V^T P^T.
// l = ones-row MFMA on pf. Masking only on the wave's diagonal tile.
// ---------------------------------------------------------------------------
__global__ __launch_bounds__(256)
void attn_mfma(const ushort_t* __restrict__ Q, const ushort_t* __restrict__ K,
               const ushort_t* __restrict__ Vt, ushort_t* __restrict__ O)
{
    __shared__ __align__(16) ushort_t sK[64 * 64];
    __shared__ __align__(16) ushort_t sVt[64 * 64];

    const int tid = threadIdx.x;
    const int lane = tid & 63;
    const int hl = lane >> 5;          // lane half
    const int lq = lane & 31;          // q-col / row-in-32 index
    const int w = tid >> 6;
    const int hb64 = blockIdx.x;       // 0..63 head-linear
    const int pair = blockIdx.y;       // 0..7
    const int h = hb64 >> 2, bb = hb64 & 3;
    const size_t hb = ((size_t)(bb * H_ + h)) * S_ * HD_;

    const int srow = lane >> 3;        // staging: row within 8-row group
    const int spc = lane & 7;          // staging: phys chunk

    short8 ones;
#pragma unroll
    for (int i = 0; i < 8; ++i) ones[i] = (short)0x3F80;   // bf16 1.0

    const f32x16 zv16 = {0,0,0,0,0,0,0,0,0,0,0,0,0,0,0,0};

    for (int pass = 0; pass < 2; ++pass) {
        const int q0 = ((pass == 0) ? (15 - pair) : pair) * 128;
        const int wq = q0 + w * 32;
        const int qg = wq + lq;        // this lane's q-row

        // Q B-frags: n=lq (q-row), k = ks*16 + hl*8 + j
        short8 qf[4];
#pragma unroll
        for (int ks = 0; ks < 4; ++ks)
            qf[ks] = *(const short8*)&Q[hb + (size_t)qg * HD_ + ks * 16 + hl * 8];

        f32x16 oa[2], la;
        oa[0] = zv16; oa[1] = zv16; la = zv16;

        const int nt = q0 / 64 + 2;
        for (int kt = 0; kt < nt; ++kt) {
            const int k0 = kt * 64;
            __syncthreads();           // protect sK/sVt reuse
            {   // stage K and V^T, XOR swizzle applied on SOURCE address
#pragma unroll
                for (int i = 0; i < 2; ++i) {
                    const int row = i * 32 + w * 8 + srow;
                    const int sc = (spc ^ (row & 7)) * 8;
                    __builtin_amdgcn_global_load_lds(
                        (gvoid*)&K[hb + (size_t)(k0 + row) * HD_ + sc],
                        (lvoid*)&sK[(i * 32 + w * 8) * 64], 16, 0, 0);
                    __builtin_amdgcn_global_load_lds(
                        (gvoid*)&Vt[hb + (size_t)row * S_ + k0 + sc],
                        (lvoid*)&sVt[(i * 32 + w * 8) * 64], 16, 0, 0);
                }
            }
            __syncthreads();

            if (k0 > wq + 31) continue;   // fully masked for this wave

            // S^T = K Q^T : rows = 64 keys (2 M-tiles), cols = 32 q
            f32x16 st[2];
            st[0] = zv16; st[1] = zv16;
            const int kr0 = lq, kr1 = 32 + lq;
#pragma unroll
            for (int ks = 0; ks < 4; ++ks) {
                const int ch = ks * 2 + hl;
                short8 ak0 = *(const short8*)&sK[kr0 * 64 + ((ch ^ (kr0 & 7)) << 3)];
                short8 ak1 = *(const short8*)&sK[kr1 * 64 + ((ch ^ (kr1 & 7)) << 3)];
                st[0] = __builtin_amdgcn_mfma_f32_32x32x16_bf16(ak0, qf[ks], st[0], 0, 0, 0);
                st[1] = __builtin_amdgcn_mfma_f32_32x32x16_bf16(ak1, qf[ks], st[1], 0, 0, 0);
            }

            // P^T in registers: exp2 (mask only on diagonal tile), perm-pack,
            // half-swap
            const bool diag = (k0 + 63 > wq);   // wave-uniform
            short8 pf[4];
#pragma unroll
            for (int nt2 = 0; nt2 < 2; ++nt2) {
                float pv[16];
                const int kb = k0 + nt2 * 32 + 4 * hl;
#pragma unroll
                for (int g = 0; g < 4; ++g)
#pragma unroll
                    for (int r = 0; r < 4; ++r) {
                        float s = st[nt2][4 * g + r];
                        if (diag) {
                            const int key = kb + 8 * g + r;
                            s = (key <= qg) ? s : -INFINITY;
                        }
                        pv[4 * g + r] = fexp2(s);
                    }
                unsigned P2[8];
#pragma unroll
                for (int g = 0; g < 4; ++g) {
                    P2[2 * g]     = pk2t(pv[4 * g + 0], pv[4 * g + 1]);
                    P2[2 * g + 1] = pk2t(pv[4 * g + 2], pv[4 * g + 3]);
                }
#if __has_builtin(__builtin_amdgcn_permlane32_swap)
                uint2v r02 = __builtin_amdgcn_permlane32_swap(P2[0], P2[2], false, false);
                uint2v r13 = __builtin_amdgcn_permlane32_swap(P2[1], P2[3], false, false);
                uint2v r46 = __builtin_amdgcn_permlane32_swap(P2[4], P2[6], false, false);
                uint2v r57 = __builtin_amdgcn_permlane32_swap(P2[5], P2[7], false, false);
                pf[nt2 * 2 + 0] = mk_frag(r02[0], r13[0], r02[1], r13[1]);
                pf[nt2 * 2 + 1] = mk_frag(r46[0], r57[0], r46[1], r57[1]);
#else
                unsigned X[8];
#pragma unroll
                for (int m = 0; m < 8; ++m) X[m] = (unsigned)__shfl_xor((int)P2[m], 32);
                pf[nt2 * 2 + 0] = hl ? mk_frag(X[2], X[3], P2[2], P2[3])
                                     : mk_frag(P2[0], P2[1], X[0], X[1]);
                pf[nt2 * 2 + 1] = hl ? mk_frag(X[6], X[7], P2[6], P2[7])
                                     : mk_frag(P2[4], P2[5], X[4], X[5]);
#endif
            }

            // O^T += V^T P^T ; l += 1^T P^T (ones-MFMA)
            const int vr0 = lq, vr1 = 32 + lq;
#pragma unroll
            for (int ks2 = 0; ks2 < 4; ++ks2) {
                const int ch = ks2 * 2 + hl;
                short8 av0 = *(const short8*)&sVt[vr0 * 64 + ((ch ^ (vr0 & 7)) << 3)];
                short8 av1 = *(const short8*)&sVt[vr1 * 64 + ((ch ^ (vr1 & 7)) << 3)];
                oa[0] = __builtin_amdgcn_mfma_f32_32x32x16_bf16(av0, pf[ks2], oa[0], 0, 0, 0);
                oa[1] = __builtin_amdgcn_mfma_f32_32x32x16_bf16(av1, pf[ks2], oa[1], 0, 0, 0);
                la    = __builtin_amdgcn_mfma_f32_32x32x16_bf16(ones, pf[ks2], la, 0, 0, 0);
            }
        }

        // epilogue: l[q] sits in every row of la; normalize, b64 stores
        const float inv = 1.f / la[0];
        ushort_t* Ob = &O[((size_t)(bb * S_ + qg)) * D_ + h * HD_];
#pragma unroll
        for (int mt = 0; mt < 2; ++mt)
#pragma unroll
            for (int g = 0; g < 4; ++g) {
                short4_t pk;
#pragma unroll
                for (int r = 0; r < 4; ++r)
                    pk[r] = (short)f2bf(oa[mt][4 * g + r] * inv);
                *(short4_t*)&Ob[mt * 32 + 8 * g + 4 * hl] = pk;
            }
    }
}

// ---------------------------------------------------------------------------
extern "C" void kernel_launch(void* const* d_in, const int* in_sizes, int n_in,
                              void* d_out, int out_size, void* d_ws, size_t ws_size,
                              hipStream_t stream)
{
    (void)in_sizes; (void)n_in; (void)out_size; (void)ws_size;
    const float* x  = (const float*)d_in[0];
    const float* Wq = (const float*)d_in[1];
    const float* Wk = (const float*)d_in[2];
    const float* Wv = (const float*)d_in[3];
    const float* Wo = (const float*)d_in[4];
    // d_in[5] = token_positions = arange(S): row index used directly.

    float* out = (float*)d_out;
    ushort_t* ws = (ushort_t*)d_ws;
    const size_t NX = (size_t)B_ * S_ * D_;   // 8M
    const size_t NW = (size_t)D_ * D_;        // 1M
    ushort_t* xb  = ws;
    ushort_t* Wqt = xb + NX;
    ushort_t* Wkt = Wqt + NW;
    ushort_t* Wvt = Wkt + NW;
    ushort_t* Wot = Wvt + NW;
    ushort_t* Qb  = Wot + NW;
    ushort_t* Kb  = Qb + NX;
    ushort_t* Vtb = Kb + NX;
    ushort_t* Ob  = Vtb + NX;   // total 44M ushort = 88 MB

    cvt_x<<<dim3(NX / 2048), 256, 0, stream>>>(x, xb);
    cvt_wt4<<<dim3(16, 16, 4), 256, 0, stream>>>(Wq, Wk, Wv, Wo, Wqt, Wkt, Wvt, Wot);

    gemm_bt<<<dim3(32, 4, 3), dim3(512), 0, stream>>>(xb, Wqt, Wkt, Wvt, Qb, Kb, Vtb, 0);
    attn_mfma<<<dim3(64, 8), 256, 0, stream>>>(Qb, Kb, Vtb, Ob);
    gemm_bt<<<dim3(32, 4, 1), dim3(512), 0, stream>>>(Ob, Wot, Wot, Wot, out, nullptr, nullptr, 3);
}

// Round 2
// 261.669 us; speedup vs baseline: 1.0512x; 1.0512x over previous
//
#include <hip/hip_runtime.h>
#include <math.h>

#define B_ 4
#define S_ 2048
#define D_ 1024
#define H_ 16
#define HD_ 64
#define ES_F 0.180336880111f    // 0.125 * log2(e), folded into Q
#define KF (-0.41524101186f)    // -log2(10000)/32

typedef unsigned short ushort_t;
typedef __attribute__((ext_vector_type(8))) short short8;    // 8 bf16 (MFMA A/B frag)
typedef __attribute__((ext_vector_type(4))) short short4_t;  // 4 bf16 packed store
typedef __attribute__((ext_vector_type(4))) float f32x4;     // 16x16 C/D frag
typedef __attribute__((ext_vector_type(16))) float f32x16;   // 32x32 C/D frag
typedef __attribute__((ext_vector_type(2))) unsigned uint2v;

typedef const void __attribute__((address_space(1))) gvoid;
typedef void __attribute__((address_space(3))) lvoid;

__device__ __forceinline__ ushort_t f2bf(float f) {
    union { float f; unsigned u; } v; v.f = f;
    unsigned r = (v.u + 0x7FFFu + ((v.u >> 16) & 1u)) >> 16;
    return (ushort_t)r;
}
__device__ __forceinline__ float fexp2(float x) {
#if __has_builtin(__builtin_amdgcn_exp2f)
    return __builtin_amdgcn_exp2f(x);   // raw v_exp_f32
#else
    return exp2f(x);
#endif
}
// pack two f32 -> bf16x2 (truncation) in one v_perm_b32
__device__ __forceinline__ unsigned pk2t(float a, float b) {
    union { float f; unsigned u; } A, Bv; A.f = a; Bv.f = b;
#if __has_builtin(__builtin_amdgcn_perm)
    return __builtin_amdgcn_perm(Bv.u, A.u, 0x07060302u);
#else
    return (A.u >> 16) | (Bv.u & 0xFFFF0000u);
#endif
}
__device__ __forceinline__ short8 mk_frag(unsigned a, unsigned b, unsigned c, unsigned d) {
    union { unsigned u[4]; short8 s; } t;
    t.u[0] = a; t.u[1] = b; t.u[2] = c; t.u[3] = d; return t.s;
}

// ---------------------------------------------------------------------------
// x fp32 -> bf16, 8 elems/thread
// ---------------------------------------------------------------------------
__global__ __launch_bounds__(256)
void cvt_x(const float* __restrict__ x, ushort_t* __restrict__ xb)
{
    const size_t i = ((size_t)blockIdx.x * 256 + threadIdx.x) * 8;
    float4 a = *(const float4*)&x[i];
    float4 b = *(const float4*)&x[i + 4];
    short8 o;
    o[0] = (short)f2bf(a.x); o[1] = (short)f2bf(a.y);
    o[2] = (short)f2bf(a.z); o[3] = (short)f2bf(a.w);
    o[4] = (short)f2bf(b.x); o[5] = (short)f2bf(b.y);
    o[6] = (short)f2bf(b.z); o[7] = (short)f2bf(b.w);
    *(short8*)&xb[i] = o;
}

// ---------------------------------------------------------------------------
// W[k][n] fp32 -> Wt[n][k] bf16 (64x64 tiles through LDS), all 4 weights
// ---------------------------------------------------------------------------
__global__ __launch_bounds__(256)
void cvt_wt4(const float* __restrict__ W0, const float* __restrict__ W1,
             const float* __restrict__ W2, const float* __restrict__ W3,
             ushort_t* __restrict__ T0, ushort_t* __restrict__ T1,
             ushort_t* __restrict__ T2, ushort_t* __restrict__ T3)
{
    const int z = blockIdx.z;
    const float* W = (z == 0) ? W0 : (z == 1) ? W1 : (z == 2) ? W2 : W3;
    ushort_t* Wt = (z == 0) ? T0 : (z == 1) ? T1 : (z == 2) ? T2 : T3;

    __shared__ __align__(16) float T[64 * 68];
    const int t = threadIdx.x;
    const int k0 = blockIdx.y * 64, n0 = blockIdx.x * 64;
    const int row = t >> 2, c0 = (t & 3) * 16;
#pragma unroll
    for (int u = 0; u < 4; ++u)
        *(float4*)&T[row * 68 + c0 + u * 4] =
            *(const float4*)&W[(size_t)(k0 + row) * D_ + n0 + c0 + u * 4];
    __syncthreads();
    const int n = t >> 2, kc = (t & 3) * 16;
    short8 o0, o1;
#pragma unroll
    for (int kk = 0; kk < 8; ++kk) o0[kk] = (short)f2bf(T[(kc + kk) * 68 + n]);
#pragma unroll
    for (int kk = 0; kk < 8; ++kk) o1[kk] = (short)f2bf(T[(kc + 8 + kk) * 68 + n]);
    *(short8*)&Wt[(size_t)(n0 + n) * D_ + k0 + kc] = o0;
    *(short8*)&Wt[(size_t)(n0 + n) * D_ + k0 + kc + 8] = o1;
}

// ---------------------------------------------------------------------------
// bf16 MFMA GEMM, 128x128 tile, BK=64, 256 thr (4 waves, 2x2), double-
// buffered LDS + T3-minimum 2-phase prefetch: STAGE(t+1) issued BEFORE
// COMPUTE(t); one __syncthreads() per tile (implicit vmcnt(0) drain).
// XOR-swizzled LDS (conflict-free, R6-verified pattern).
//
// Operand orientation per mode:
//   modes 0/1 (Q,K) and 3 (proj): SWAPPED — A-frag = Wt rows (features),
//     B-frag = x rows (tokens) -> C[feature][token].  A thread's register
//     run of 4 consecutive FEATURES holds both elements of each RoPE
//     rotation pair -> rotation fully in-register (no shfl), short4/float4
//     stores (16 store insts vs 128 scalar).
//   mode 2 (V): original orientation -> C[token][feature], token-contiguous
//     short4 stores into V^T [b][h][d][s].
// C/D layout (32x32x16): col=lane&31, row=(reg&3)+8*(reg>>2)+4*(lane>>5).
// Grid: x = token-tile (64), y = feature-tile (8), z = weight select.
// ---------------------------------------------------------------------------

#define STAGE(tt, Ad, Bd) {                                                    \
    const int kk_ = (tt) * 64;                                                 \
    _Pragma("unroll") for (int i_ = 0; i_ < 4; ++i_) {                         \
        const int rb_ = (i_ * 4 + w) * 8;                                      \
        __builtin_amdgcn_global_load_lds(                                      \
            (gvoid*)&pA[(size_t)(aBase + rb_ + srow) * D_ + kk_ + sch],        \
            (lvoid*)&(Ad)[rb_ * 64], 16, 0, 0);                                \
        __builtin_amdgcn_global_load_lds(                                      \
            (gvoid*)&pB[(size_t)(bBase + rb_ + srow) * D_ + kk_ + sch],        \
            (lvoid*)&(Bd)[rb_ * 64], 16, 0, 0);                                \
    } }

#define COMPUTE(Ab, Bb) {                                                      \
    _Pragma("unroll") for (int ks = 0; ks < 4; ++ks) {                         \
        const int xr_ = (((ks * 2 + hl) ^ (lq & 7)) << 3);                     \
        short8 af0 = *(const short8*)&(Ab)[(wr * 64 + lq) * 64 + xr_];         \
        short8 af1 = *(const short8*)&(Ab)[(wr * 64 + 32 + lq) * 64 + xr_];    \
        short8 bf0 = *(const short8*)&(Bb)[(wc * 64 + lq) * 64 + xr_];         \
        short8 bf1 = *(const short8*)&(Bb)[(wc * 64 + 32 + lq) * 64 + xr_];    \
        acc[0][0] = __builtin_amdgcn_mfma_f32_32x32x16_bf16(af0, bf0, acc[0][0], 0, 0, 0); \
        acc[0][1] = __builtin_amdgcn_mfma_f32_32x32x16_bf16(af0, bf1, acc[0][1], 0, 0, 0); \
        acc[1][0] = __builtin_amdgcn_mfma_f32_32x32x16_bf16(af1, bf0, acc[1][0], 0, 0, 0); \
        acc[1][1] = __builtin_amdgcn_mfma_f32_32x32x16_bf16(af1, bf1, acc[1][1], 0, 0, 0); \
    } }

__global__ __launch_bounds__(256, 2)
void gemm_bt(const ushort_t* __restrict__ A,
             const ushort_t* __restrict__ W0, const ushort_t* __restrict__ W1,
             const ushort_t* __restrict__ W2,
             void* __restrict__ d0, void* __restrict__ d1, void* __restrict__ d2,
             const int mode_base)
{
    __shared__ __align__(16) ushort_t As[2 * 128 * 64];   // 32 KiB
    __shared__ __align__(16) ushort_t Bs[2 * 128 * 64];   // 32 KiB

    const int tid = threadIdx.x;
    const int lane = tid & 63;
    const int hl = lane >> 5;          // lane half
    const int lq = lane & 31;          // row/col within 32-tile
    const int w = tid >> 6, wr = w >> 1, wc = w & 1;
    const int z = blockIdx.z;
    const ushort_t* Wt = (z == 0) ? W0 : (z == 1) ? W1 : W2;
    const int mode = mode_base + z;
    const bool sw = (mode != 2);       // swapped orientation for Q/K/proj

    const int tokT = blockIdx.x * 128, featT = blockIdx.y * 128;
    const ushort_t* pA = sw ? Wt : A;
    const ushort_t* pB = sw ? A : Wt;
    const int aBase = sw ? featT : tokT;
    const int bBase = sw ? tokT : featT;

    const f32x16 zv16 = {0,0,0,0,0,0,0,0,0,0,0,0,0,0,0,0};
    f32x16 acc[2][2];
    acc[0][0] = zv16; acc[0][1] = zv16; acc[1][0] = zv16; acc[1][1] = zv16;

    const int srow = lane >> 3;              // row within 8-row staging group
    const int spc  = lane & 7;               // phys chunk this lane fills
    const int sch  = (spc ^ srow) * 8;       // logical chunk to fetch (swizzle)

    ushort_t* A0 = As;  ushort_t* A1 = As + 128 * 64;
    ushort_t* B0 = Bs;  ushort_t* B1 = Bs + 128 * 64;

    STAGE(0, A0, B0);
    __syncthreads();

#pragma unroll 1
    for (int t2 = 0; t2 < 8; ++t2) {
        STAGE(2 * t2 + 1, A1, B1);     // prefetch next tile under compute
        COMPUTE(A0, B0);
        __syncthreads();               // implicit vmcnt(0)+lgkmcnt(0) drain
        if (t2 < 7) STAGE(2 * t2 + 2, A0, B0);
        COMPUTE(A1, B1);
        __syncthreads();
    }

    if (mode == 2) {
        // original orientation: rows = tokens, cols = features -> V^T store
#pragma unroll
        for (int tn = 0; tn < 2; ++tn) {
            const int n = bBase + wc * 64 + tn * 32 + lq;
            const int h = n >> 6, dd = n & 63;
#pragma unroll
            for (int tm = 0; tm < 2; ++tm) {
                const int mb = aBase + wr * 64 + tm * 32 + 4 * hl;
#pragma unroll
                for (int g = 0; g < 4; ++g) {
                    const int m_base = mb + 8 * g;
                    const int bb2 = m_base >> 11, s0 = m_base & (S_ - 1);
                    short4_t pk;
#pragma unroll
                    for (int r = 0; r < 4; ++r)
                        pk[r] = (short)f2bf(acc[tm][tn][4 * g + r]);
                    *(short4_t*)&((ushort_t*)d2)[(((size_t)bb2 * H_ + h) * HD_ + dd) * S_ + s0] = pk;
                }
            }
        }
    } else if (mode == 3) {
        // swapped: rows = output features, cols = tokens -> float4 stores
        float* outp = (float*)d0;
#pragma unroll
        for (int tn = 0; tn < 2; ++tn) {
            const int tok = bBase + wc * 64 + tn * 32 + lq;
#pragma unroll
            for (int tm = 0; tm < 2; ++tm) {
                const int fb = aBase + wr * 64 + tm * 32 + 4 * hl;
#pragma unroll
                for (int g = 0; g < 4; ++g) {
                    f32x4 v;
                    v[0] = acc[tm][tn][4 * g + 0];
                    v[1] = acc[tm][tn][4 * g + 1];
                    v[2] = acc[tm][tn][4 * g + 2];
                    v[3] = acc[tm][tn][4 * g + 3];
                    *(f32x4*)&outp[(size_t)tok * D_ + fb + 8 * g] = v;
                }
            }
        }
    } else {
        // swapped Q/K: rows = features (RoPE pairs in-register), cols = tokens
        ushort_t* dst = (mode == 0) ? (ushort_t*)d0 : (ushort_t*)d1;
        const float sc = (mode == 0) ? ES_F : 1.0f;
#pragma unroll
        for (int tn = 0; tn < 2; ++tn) {
            const int tok = bBase + wc * 64 + tn * 32 + lq;
            const int bb2 = tok >> 11, s0 = tok & (S_ - 1);
            const float fs0 = (float)s0;
#pragma unroll
            for (int tm = 0; tm < 2; ++tm) {
                const int fb = aBase + wr * 64 + tm * 32 + 4 * hl;
                const int h = fb >> 6;
                const int ddb = fb & 63;        // {0,4,32,36}: never crosses head
                ushort_t* dp = &dst[(((size_t)bb2 * H_ + h) * S_ + s0) * HD_];
#pragma unroll
                for (int g = 0; g < 4; ++g) {
                    const int dd = ddb + 8 * g;
                    const int jj = dd >> 1;     // rotation pair indices jj, jj+1
                    const float if0 = exp2f(KF * (float)jj);
                    const float if1 = exp2f(KF * (float)(jj + 1));
                    float sn0, cs0, sn1, cs1;
                    __sincosf(fs0 * if0, &sn0, &cs0);
                    __sincosf(fs0 * if1, &sn1, &cs1);
                    const float x0 = acc[tm][tn][4 * g + 0];
                    const float x1 = acc[tm][tn][4 * g + 1];
                    const float x2 = acc[tm][tn][4 * g + 2];
                    const float x3 = acc[tm][tn][4 * g + 3];
                    short4_t pk;
                    pk[0] = (short)f2bf((x0 * cs0 - x1 * sn0) * sc);
                    pk[1] = (short)f2bf((x0 * sn0 + x1 * cs0) * sc);
                    pk[2] = (short)f2bf((x2 * cs1 - x3 * sn1) * sc);
                    pk[3] = (short)f2bf((x2 * sn1 + x3 * cs1) * sc);
                    *(short4_t*)&dp[dd] = pk;
                }
            }
        }
    }
}

// ---------------------------------------------------------------------------
// MFMA flash attention, S^T formulation, P fully in registers.
// Grid: x = head-linear (64) -> id%8 = head%8 (XCD K/V L2 locality).
// y = causal pair (8). Block = 4 waves; two 128-row q-tiles per block
// (pair j, 15-j) -> uniform 34 stages/block. S^T = K Q^T (32x32x16); P^T
// built in-register; half-swap via v_permlane32_swap (VALU pipe, one op
// yields both frag words) with shfl fallback. O^T = V^T P^T.
// l = ones-row MFMA on pf. Masking only on the wave's diagonal tile.
// ---------------------------------------------------------------------------
__global__ __launch_bounds__(256)
void attn_mfma(const ushort_t* __restrict__ Q, const ushort_t* __restrict__ K,
               const ushort_t* __restrict__ Vt, ushort_t* __restrict__ O)
{
    __shared__ __align__(16) ushort_t sK[64 * 64];
    __shared__ __align__(16) ushort_t sVt[64 * 64];

    const int tid = threadIdx.x;
    const int lane = tid & 63;
    const int hl = lane >> 5;          // lane half
    const int lq = lane & 31;          // q-col / row-in-32 index
    const int w = tid >> 6;
    const int hb64 = blockIdx.x;       // 0..63 head-linear
    const int pair = blockIdx.y;       // 0..7
    const int h = hb64 >> 2, bb = hb64 & 3;
    const size_t hb = ((size_t)(bb * H_ + h)) * S_ * HD_;

    const int srow = lane >> 3;        // staging: row within 8-row group
    const int spc = lane & 7;          // staging: phys chunk

    short8 ones;
#pragma unroll
    for (int i = 0; i < 8; ++i) ones[i] = (short)0x3F80;   // bf16 1.0

    const f32x16 zv16 = {0,0,0,0,0,0,0,0,0,0,0,0,0,0,0,0};

    for (int pass = 0; pass < 2; ++pass) {
        const int q0 = ((pass == 0) ? (15 - pair) : pair) * 128;
        const int wq = q0 + w * 32;
        const int qg = wq + lq;        // this lane's q-row

        // Q B-frags: n=lq (q-row), k = ks*16 + hl*8 + j
        short8 qf[4];
#pragma unroll
        for (int ks = 0; ks < 4; ++ks)
            qf[ks] = *(const short8*)&Q[hb + (size_t)qg * HD_ + ks * 16 + hl * 8];

        f32x16 oa[2], la;
        oa[0] = zv16; oa[1] = zv16; la = zv16;

        const int nt = q0 / 64 + 2;
        for (int kt = 0; kt < nt; ++kt) {
            const int k0 = kt * 64;
            __syncthreads();           // protect sK/sVt reuse
            {   // stage K and V^T, XOR swizzle applied on SOURCE address
#pragma unroll
                for (int i = 0; i < 2; ++i) {
                    const int row = i * 32 + w * 8 + srow;
                    const int sc = (spc ^ (row & 7)) * 8;
                    __builtin_amdgcn_global_load_lds(
                        (gvoid*)&K[hb + (size_t)(k0 + row) * HD_ + sc],
                        (lvoid*)&sK[(i * 32 + w * 8) * 64], 16, 0, 0);
                    __builtin_amdgcn_global_load_lds(
                        (gvoid*)&Vt[hb + (size_t)row * S_ + k0 + sc],
                        (lvoid*)&sVt[(i * 32 + w * 8) * 64], 16, 0, 0);
                }
            }
            __syncthreads();

            if (k0 > wq + 31) continue;   // fully masked for this wave

            // S^T = K Q^T : rows = 64 keys (2 M-tiles), cols = 32 q
            f32x16 st[2];
            st[0] = zv16; st[1] = zv16;
            const int kr0 = lq, kr1 = 32 + lq;
#pragma unroll
            for (int ks = 0; ks < 4; ++ks) {
                const int ch = ks * 2 + hl;
                short8 ak0 = *(const short8*)&sK[kr0 * 64 + ((ch ^ (kr0 & 7)) << 3)];
                short8 ak1 = *(const short8*)&sK[kr1 * 64 + ((ch ^ (kr1 & 7)) << 3)];
                st[0] = __builtin_amdgcn_mfma_f32_32x32x16_bf16(ak0, qf[ks], st[0], 0, 0, 0);
                st[1] = __builtin_amdgcn_mfma_f32_32x32x16_bf16(ak1, qf[ks], st[1], 0, 0, 0);
            }

            // P^T in registers: exp2 (mask only on diagonal tile), perm-pack,
            // half-swap
            const bool diag = (k0 + 63 > wq);   // wave-uniform
            short8 pf[4];
#pragma unroll
            for (int nt2 = 0; nt2 < 2; ++nt2) {
                float pv[16];
                const int kb = k0 + nt2 * 32 + 4 * hl;
#pragma unroll
                for (int g = 0; g < 4; ++g)
#pragma unroll
                    for (int r = 0; r < 4; ++r) {
                        float s = st[nt2][4 * g + r];
                        if (diag) {
                            const int key = kb + 8 * g + r;
                            s = (key <= qg) ? s : -INFINITY;
                        }
                        pv[4 * g + r] = fexp2(s);
                    }
                unsigned P2[8];
#pragma unroll
                for (int g = 0; g < 4; ++g) {
                    P2[2 * g]     = pk2t(pv[4 * g + 0], pv[4 * g + 1]);
                    P2[2 * g + 1] = pk2t(pv[4 * g + 2], pv[4 * g + 3]);
                }
#if __has_builtin(__builtin_amdgcn_permlane32_swap)
                uint2v r02 = __builtin_amdgcn_permlane32_swap(P2[0], P2[2], false, false);
                uint2v r13 = __builtin_amdgcn_permlane32_swap(P2[1], P2[3], false, false);
                uint2v r46 = __builtin_amdgcn_permlane32_swap(P2[4], P2[6], false, false);
                uint2v r57 = __builtin_amdgcn_permlane32_swap(P2[5], P2[7], false, false);
                pf[nt2 * 2 + 0] = mk_frag(r02[0], r13[0], r02[1], r13[1]);
                pf[nt2 * 2 + 1] = mk_frag(r46[0], r57[0], r46[1], r57[1]);
#else
                unsigned X[8];
#pragma unroll
                for (int m = 0; m < 8; ++m) X[m] = (unsigned)__shfl_xor((int)P2[m], 32);
                pf[nt2 * 2 + 0] = hl ? mk_frag(X[2], X[3], P2[2], P2[3])
                                     : mk_frag(P2[0], P2[1], X[0], X[1]);
                pf[nt2 * 2 + 1] = hl ? mk_frag(X[6], X[7], P2[6], P2[7])
                                     : mk_frag(P2[4], P2[5], X[4], X[5]);
#endif
            }

            // O^T += V^T P^T ; l += 1^T P^T (ones-MFMA)
            const int vr0 = lq, vr1 = 32 + lq;
#pragma unroll
            for (int ks2 = 0; ks2 < 4; ++ks2) {
                const int ch = ks2 * 2 + hl;
                short8 av0 = *(const short8*)&sVt[vr0 * 64 + ((ch ^ (vr0 & 7)) << 3)];
                short8 av1 = *(const short8*)&sVt[vr1 * 64 + ((ch ^ (vr1 & 7)) << 3)];
                oa[0] = __builtin_amdgcn_mfma_f32_32x32x16_bf16(av0, pf[ks2], oa[0], 0, 0, 0);
                oa[1] = __builtin_amdgcn_mfma_f32_32x32x16_bf16(av1, pf[ks2], oa[1], 0, 0, 0);
                la    = __builtin_amdgcn_mfma_f32_32x32x16_bf16(ones, pf[ks2], la, 0, 0, 0);
            }
        }

        // epilogue: l[q] sits in every row of la; normalize, b64 stores
        const float inv = 1.f / la[0];
        ushort_t* Ob = &O[((size_t)(bb * S_ + qg)) * D_ + h * HD_];
#pragma unroll
        for (int mt = 0; mt < 2; ++mt)
#pragma unroll
            for (int g = 0; g < 4; ++g) {
                short4_t pk;
#pragma unroll
                for (int r = 0; r < 4; ++r)
                    pk[r] = (short)f2bf(oa[mt][4 * g + r] * inv);
                *(short4_t*)&Ob[mt * 32 + 8 * g + 4 * hl] = pk;
            }
    }
}

// ---------------------------------------------------------------------------
extern "C" void kernel_launch(void* const* d_in, const int* in_sizes, int n_in,
                              void* d_out, int out_size, void* d_ws, size_t ws_size,
                              hipStream_t stream)
{
    (void)in_sizes; (void)n_in; (void)out_size; (void)ws_size;
    const float* x  = (const float*)d_in[0];
    const float* Wq = (const float*)d_in[1];
    const float* Wk = (const float*)d_in[2];
    const float* Wv = (const float*)d_in[3];
    const float* Wo = (const float*)d_in[4];
    // d_in[5] = token_positions = arange(S): row index used directly.

    float* out = (float*)d_out;
    ushort_t* ws = (ushort_t*)d_ws;
    const size_t NX = (size_t)B_ * S_ * D_;   // 8M
    const size_t NW = (size_t)D_ * D_;        // 1M
    ushort_t* xb  = ws;
    ushort_t* Wqt = xb + NX;
    ushort_t* Wkt = Wqt + NW;
    ushort_t* Wvt = Wkt + NW;
    ushort_t* Wot = Wvt + NW;
    ushort_t* Qb  = Wot + NW;
    ushort_t* Kb  = Qb + NX;
    ushort_t* Vtb = Kb + NX;
    ushort_t* Ob  = Vtb + NX;   // total 44M ushort = 88 MB

    cvt_x<<<dim3(NX / 2048), 256, 0, stream>>>(x, xb);
    cvt_wt4<<<dim3(16, 16, 4), 256, 0, stream>>>(Wq, Wk, Wv, Wo, Wqt, Wkt, Wvt, Wot);

    gemm_bt<<<dim3(64, 8, 3), 256, 0, stream>>>(xb, Wqt, Wkt, Wvt, Qb, Kb, Vtb, 0);
    attn_mfma<<<dim3(64, 8), 256, 0, stream>>>(Qb, Kb, Vtb, Ob);
    gemm_bt<<<dim3(64, 8, 1), 256, 0, stream>>>(Ob, Wot, Wot, Wot, out, nullptr, nullptr, 3);
}